// Round 2
// baseline (1035.282 us; speedup 1.0000x reference)
//
#include <hip/hip_runtime.h>

#define N_NODES 100000
#define E_EDGES 3200000
#define F_IN    1433
#define K_PAD   1440   // 45*32, zero-padded K
#define NSTEP   45
#define NCH     98     // scan chunks of 1024

typedef _Float16 f16x4 __attribute__((ext_vector_type(4)));
typedef float    f32x4 __attribute__((ext_vector_type(4)));

// ---------------- W1^T fp16 [64][K_PAD], zero-padded ----------------
__global__ void k_prep_w1t(const float* __restrict__ w1, _Float16* __restrict__ w1t) {
    int idx = blockIdx.x * 256 + threadIdx.x;           // 64*1440 = 92160
    if (idx >= 64 * K_PAD) return;
    int n = idx / K_PAD, k = idx % K_PAD;
    float v = (k < F_IN) ? w1[(size_t)k * 64 + n] : 0.f;
    w1t[idx] = (_Float16)v;
}

__global__ void k_zero(int* __restrict__ counts) {
    int i = blockIdx.x * 256 + threadIdx.x;
    if (i < N_NODES) counts[i] = 0;
}

__global__ void k_hist(const int* __restrict__ dst, int* __restrict__ counts) {
    int e = blockIdx.x * 256 + threadIdx.x;
    if (e < E_EDGES) atomicAdd(&counts[dst[e]], 1);
}

// ---------------- exclusive scan of counts (chunked) ----------------
__global__ void k_scan_a(const int* __restrict__ counts, int* __restrict__ csum) {
    __shared__ int sh[256];
    int b = blockIdx.x, t = threadIdx.x;
    int s = 0;
    for (int j = 0; j < 4; ++j) {
        int idx = b * 1024 + j * 256 + t;
        if (idx < N_NODES) s += counts[idx];
    }
    sh[t] = s; __syncthreads();
    for (int off = 128; off > 0; off >>= 1) {
        if (t < off) sh[t] += sh[t + off];
        __syncthreads();
    }
    if (t == 0) csum[b] = sh[0];
}

__global__ void k_scan_b(int* __restrict__ csum) {
    if (threadIdx.x == 0 && blockIdx.x == 0) {
        int run = 0;
        for (int i = 0; i < NCH; ++i) { int t = csum[i]; csum[i] = run; run += t; }
    }
}

__global__ void k_scan_c(const int* __restrict__ counts, const int* __restrict__ csum,
                         int* __restrict__ offsets, int* __restrict__ cursor) {
    __shared__ int sh[256];
    int b = blockIdx.x, t = threadIdx.x;
    int base = b * 1024 + t * 4;
    int c0 = (base + 0 < N_NODES) ? counts[base + 0] : 0;
    int c1 = (base + 1 < N_NODES) ? counts[base + 1] : 0;
    int c2 = (base + 2 < N_NODES) ? counts[base + 2] : 0;
    int c3 = (base + 3 < N_NODES) ? counts[base + 3] : 0;
    int tot = c0 + c1 + c2 + c3;
    sh[t] = tot; __syncthreads();
    for (int off = 1; off < 256; off <<= 1) {
        int v = (t >= off) ? sh[t - off] : 0;
        __syncthreads();
        sh[t] += v;
        __syncthreads();
    }
    int excl = sh[t] - tot;
    int o = csum[b] + excl;
    if (base + 0 < N_NODES) { offsets[base + 0] = o;            cursor[base + 0] = o; }
    if (base + 1 < N_NODES) { int q = o + c0;      offsets[base + 1] = q; cursor[base + 1] = q; }
    if (base + 2 < N_NODES) { int q = o + c0 + c1; offsets[base + 2] = q; cursor[base + 2] = q; }
    if (base + 3 < N_NODES) { int q = o + c0 + c1 + c2; offsets[base + 3] = q; cursor[base + 3] = q; }
}

__global__ void k_scatter(const int* __restrict__ src, const int* __restrict__ dst,
                          int* __restrict__ cursor, int* __restrict__ sorted_src) {
    int e = blockIdx.x * 256 + threadIdx.x;
    if (e < E_EDGES) {
        int d = dst[e];
        int pos = atomicAdd(&cursor[d], 1);
        sorted_src[pos] = src[e];
    }
}

// ---------------- GEMM1: h1[N,64] = x @ W1  (fp16 MFMA, fp32 accum) ----------------
__global__ __launch_bounds__(256) void k_gemm1(const float* __restrict__ x,
                                               const _Float16* __restrict__ w1t,
                                               float* __restrict__ h1) {
    __shared__ _Float16 As[128 * 40];   // 128 rows x 32 k, padded stride 40 halves
    const int tid  = threadIdx.x;
    const int lane = tid & 63;
    const int wave = tid >> 6;
    const int l16  = lane & 15;
    const int l4   = lane >> 4;
    const int row0 = blockIdx.x * 128;

    f32x4 acc[2][4] = {};

    const int srow = tid >> 3;         // 0..31
    const int scol = (tid & 7) * 4;    // 0..28 step 4

    for (int ks = 0; ks < NSTEP; ++ks) {
        float v[4][4];
        #pragma unroll
        for (int i = 0; i < 4; ++i) {
            int gr = row0 + srow + i * 32;
            gr = gr < N_NODES ? gr : N_NODES - 1;
            const float* xp = x + (size_t)gr * F_IN;
            int gk = ks * 32 + scol;
            #pragma unroll
            for (int j = 0; j < 4; ++j) {
                int k = gk + j;
                v[i][j] = (k < F_IN) ? xp[k] : 0.f;
            }
        }
        __syncthreads();
        #pragma unroll
        for (int i = 0; i < 4; ++i) {
            f16x4 hv = { (_Float16)v[i][0], (_Float16)v[i][1],
                         (_Float16)v[i][2], (_Float16)v[i][3] };
            *(f16x4*)(&As[(srow + i * 32) * 40 + scol]) = hv;
        }
        __syncthreads();
        #pragma unroll
        for (int kb = 0; kb < 2; ++kb) {
            #pragma unroll
            for (int fn = 0; fn < 4; ++fn) {
                f16x4 bfr = *(const f16x4*)(w1t + (size_t)(fn * 16 + l16) * K_PAD
                                            + ks * 32 + kb * 16 + l4 * 4);
                #pragma unroll
                for (int fm = 0; fm < 2; ++fm) {
                    f16x4 afr = *(const f16x4*)(&As[(wave * 32 + fm * 16 + l16) * 40
                                                    + kb * 16 + l4 * 4]);
                    acc[fm][fn] = __builtin_amdgcn_mfma_f32_16x16x16f16(afr, bfr, acc[fm][fn], 0, 0, 0);
                }
            }
        }
    }
    #pragma unroll
    for (int fm = 0; fm < 2; ++fm) {
        int rbase = row0 + wave * 32 + fm * 16 + l4 * 4;
        #pragma unroll
        for (int j = 0; j < 4; ++j) {
            int r = rbase + j;
            if (r < N_NODES) {
                #pragma unroll
                for (int fn = 0; fn < 4; ++fn)
                    h1[(size_t)r * 64 + fn * 16 + l16] = acc[fm][fn][j];
            }
        }
    }
}

// ---------------- per-node attention coefficients, layer 1 ----------------
__global__ void k_att1(const float* __restrict__ h1, const float* __restrict__ att_src,
                       const float* __restrict__ att_dst,
                       float* __restrict__ a_s, float* __restrict__ a_d) {
    int n = blockIdx.x * 256 + threadIdx.x;
    if (n >= N_NODES) return;
    const float4* hp = (const float4*)(h1 + (size_t)n * 64);
    #pragma unroll
    for (int h = 0; h < 8; ++h) {
        float4 a = hp[h * 2], b = hp[h * 2 + 1];
        const float* as = att_src + h * 8;
        const float* ad = att_dst + h * 8;
        float s = a.x*as[0]+a.y*as[1]+a.z*as[2]+a.w*as[3]+b.x*as[4]+b.y*as[5]+b.z*as[6]+b.w*as[7];
        float d = a.x*ad[0]+a.y*ad[1]+a.z*ad[2]+a.w*ad[3]+b.x*ad[4]+b.y*ad[5]+b.z*ad[6]+b.w*ad[7];
        a_s[n * 8 + h] = s;
        a_d[n * 8 + h] = d;
    }
}

// ---------------- layer-1 aggregate + ELU + layer-2 prep (8 lanes/node = 1/head) ----------------
__global__ __launch_bounds__(256) void k_agg1(
    const int* __restrict__ offsets, const int* __restrict__ counts,
    const int* __restrict__ sorted_src,
    const float* __restrict__ a_s1, const float* __restrict__ a_d1,
    const float* __restrict__ h1, const float* __restrict__ b1,
    const float* __restrict__ w2, const float* __restrict__ att_src2,
    const float* __restrict__ att_dst2,
    float* __restrict__ g, float* __restrict__ a_s2, float* __restrict__ a_d2) {
    const int tid  = threadIdx.x;
    const int lane = tid & 63;
    const int wave = tid >> 6;
    const int grp  = lane >> 3;
    const int h    = lane & 7;
    const int n    = blockIdx.x * 32 + wave * 8 + grp;   // 3125*32 = 100000 exact
    const int start = offsets[n];
    const int cnt   = counts[n];
    const float adn = a_d1[n * 8 + h];
    float es = a_s1[n * 8 + h] + adn;
    const float e_self = es > 0.f ? es : 0.2f * es;
    float m = e_self;
    for (int i = 0; i < cnt; ++i) {
        int s = sorted_src[start + i];
        float e = a_s1[s * 8 + h] + adn;
        e = e > 0.f ? e : 0.2f * e;
        m = fmaxf(m, e);
    }
    float denom = __expf(e_self - m);
    float acc[8];
    {
        const float4* hp = (const float4*)(h1 + (size_t)n * 64 + h * 8);
        float4 A = hp[0], B = hp[1];
        acc[0]=denom*A.x; acc[1]=denom*A.y; acc[2]=denom*A.z; acc[3]=denom*A.w;
        acc[4]=denom*B.x; acc[5]=denom*B.y; acc[6]=denom*B.z; acc[7]=denom*B.w;
    }
    for (int i = 0; i < cnt; ++i) {
        int s = sorted_src[start + i];
        float e = a_s1[s * 8 + h] + adn;
        e = e > 0.f ? e : 0.2f * e;
        float p = __expf(e - m);
        denom += p;
        const float4* hp = (const float4*)(h1 + (size_t)s * 64 + h * 8);
        float4 A = hp[0], B = hp[1];
        acc[0]+=p*A.x; acc[1]+=p*A.y; acc[2]+=p*A.z; acc[3]+=p*A.w;
        acc[4]+=p*B.x; acc[5]+=p*B.y; acc[6]+=p*B.z; acc[7]+=p*B.w;
    }
    float inv = 1.f / (denom + 1e-16f);
    float hc[8];
    #pragma unroll
    for (int c = 0; c < 8; ++c) {
        float v = acc[c] * inv;
        v += __shfl_xor(v, 1, 8);
        v += __shfl_xor(v, 2, 8);
        v += __shfl_xor(v, 4, 8);          // sum over heads
        float o = 0.125f * v + b1[c];
        hc[c] = o > 0.f ? o : expm1f(o);   // ELU
    }
    float gv[7]; float s2 = 0.f, d2 = 0.f;
    #pragma unroll
    for (int j = 0; j < 7; ++j) {
        float t = 0.f;
        #pragma unroll
        for (int c = 0; c < 8; ++c) t += hc[c] * w2[c * 7 + j];
        gv[j] = t;
        s2 += t * att_src2[j];
        d2 += t * att_dst2[j];
    }
    if (h < 7) g[n * 8 + h] = gv[h];
    else       g[n * 8 + 7] = 0.f;
    if (h == 0) { a_s2[n] = s2; a_d2[n] = d2; }
}

// ---------------- layer-2 aggregate + log_softmax (8 lanes/node, edges strided) ----------------
__global__ __launch_bounds__(256) void k_agg2(
    const int* __restrict__ offsets, const int* __restrict__ counts,
    const int* __restrict__ sorted_src,
    const float* __restrict__ a_s2, const float* __restrict__ a_d2,
    const float* __restrict__ g, const float* __restrict__ b2,
    float* __restrict__ outp) {
    const int tid  = threadIdx.x;
    const int lane = tid & 63;
    const int wave = tid >> 6;
    const int grp  = lane >> 3;
    const int s    = lane & 7;
    const int n    = blockIdx.x * 32 + wave * 8 + grp;
    const int start = offsets[n];
    const int cnt   = counts[n];
    const float adn = a_d2[n];
    float et = a_s2[n] + adn;
    const float e_self = et > 0.f ? et : 0.2f * et;
    float m = (s == 0) ? e_self : -1e30f;
    for (int i = s; i < cnt; i += 8) {
        int sc = sorted_src[start + i];
        float e = a_s2[sc] + adn;
        e = e > 0.f ? e : 0.2f * e;
        m = fmaxf(m, e);
    }
    m = fmaxf(m, __shfl_xor(m, 1, 8));
    m = fmaxf(m, __shfl_xor(m, 2, 8));
    m = fmaxf(m, __shfl_xor(m, 4, 8));
    float denom = 0.f;
    float acc[8] = {0.f,0.f,0.f,0.f,0.f,0.f,0.f,0.f};
    if (s == 0) {
        float p = __expf(e_self - m);
        denom = p;
        const float4* gp = (const float4*)(g + (size_t)n * 8);
        float4 A = gp[0], B = gp[1];
        acc[0]=p*A.x; acc[1]=p*A.y; acc[2]=p*A.z; acc[3]=p*A.w;
        acc[4]=p*B.x; acc[5]=p*B.y; acc[6]=p*B.z; acc[7]=p*B.w;
    }
    for (int i = s; i < cnt; i += 8) {
        int sc = sorted_src[start + i];
        float e = a_s2[sc] + adn;
        e = e > 0.f ? e : 0.2f * e;
        float p = __expf(e - m);
        denom += p;
        const float4* gp = (const float4*)(g + (size_t)sc * 8);
        float4 A = gp[0], B = gp[1];
        acc[0]+=p*A.x; acc[1]+=p*A.y; acc[2]+=p*A.z; acc[3]+=p*A.w;
        acc[4]+=p*B.x; acc[5]+=p*B.y; acc[6]+=p*B.z; acc[7]+=p*B.w;
    }
    denom += __shfl_xor(denom, 1, 8);
    denom += __shfl_xor(denom, 2, 8);
    denom += __shfl_xor(denom, 4, 8);
    #pragma unroll
    for (int c = 0; c < 8; ++c) {
        acc[c] += __shfl_xor(acc[c], 1, 8);
        acc[c] += __shfl_xor(acc[c], 2, 8);
        acc[c] += __shfl_xor(acc[c], 4, 8);
    }
    float inv = 1.f / (denom + 1e-16f);
    float o[7]; float mx = -1e30f;
    #pragma unroll
    for (int c = 0; c < 7; ++c) { o[c] = acc[c] * inv + b2[c]; mx = fmaxf(mx, o[c]); }
    float se = 0.f;
    #pragma unroll
    for (int c = 0; c < 7; ++c) se += __expf(o[c] - mx);
    float ls = mx + logf(se);
    if (s < 7) outp[n * 7 + s] = o[s] - ls;
}

extern "C" void kernel_launch(void* const* d_in, const int* in_sizes, int n_in,
                              void* d_out, int out_size, void* d_ws, size_t ws_size,
                              hipStream_t stream) {
    const float* x        = (const float*)d_in[0];
    const int*   ei       = (const int*)d_in[1];
    const float* W1       = (const float*)d_in[2];
    const float* att_src1 = (const float*)d_in[3];
    const float* att_dst1 = (const float*)d_in[4];
    const float* b1       = (const float*)d_in[5];
    const float* W2       = (const float*)d_in[6];
    const float* att_src2 = (const float*)d_in[7];
    const float* att_dst2 = (const float*)d_in[8];
    const float* b2       = (const float*)d_in[9];
    const int* src = ei;
    const int* dst = ei + E_EDGES;

    char* ws = (char*)d_ws;
    size_t off = 0;
    auto alloc = [&](size_t bytes) -> char* {
        char* p = ws + off;
        off = (off + bytes + 255) & ~(size_t)255;
        return p;
    };
    float*    h1         = (float*)   alloc((size_t)N_NODES * 64 * 4);
    float*    a_s1       = (float*)   alloc((size_t)N_NODES * 8 * 4);
    float*    a_d1       = (float*)   alloc((size_t)N_NODES * 8 * 4);
    _Float16* w1t        = (_Float16*)alloc((size_t)64 * K_PAD * 2);
    int*      counts     = (int*)     alloc((size_t)N_NODES * 4);
    int*      offsets    = (int*)     alloc((size_t)N_NODES * 4);
    int*      cursor     = (int*)     alloc((size_t)N_NODES * 4);
    int*      csum       = (int*)     alloc((size_t)NCH * 4);
    int*      sorted_src = (int*)     alloc((size_t)E_EDGES * 4);
    float*    gbuf       = (float*)   alloc((size_t)N_NODES * 8 * 4);
    float*    a_s2       = (float*)   alloc((size_t)N_NODES * 4);
    float*    a_d2       = (float*)   alloc((size_t)N_NODES * 4);
    float*    outp       = (float*)d_out;

    hipLaunchKernelGGL(k_prep_w1t, dim3(360),   dim3(256), 0, stream, W1, w1t);
    hipLaunchKernelGGL(k_zero,     dim3(391),   dim3(256), 0, stream, counts);
    hipLaunchKernelGGL(k_hist,     dim3(12500), dim3(256), 0, stream, dst, counts);
    hipLaunchKernelGGL(k_scan_a,   dim3(NCH),   dim3(256), 0, stream, counts, csum);
    hipLaunchKernelGGL(k_scan_b,   dim3(1),     dim3(1),   0, stream, csum);
    hipLaunchKernelGGL(k_scan_c,   dim3(NCH),   dim3(256), 0, stream, counts, csum, offsets, cursor);
    hipLaunchKernelGGL(k_scatter,  dim3(12500), dim3(256), 0, stream, src, dst, cursor, sorted_src);
    hipLaunchKernelGGL(k_gemm1,    dim3(782),   dim3(256), 0, stream, x, w1t, h1);
    hipLaunchKernelGGL(k_att1,     dim3(391),   dim3(256), 0, stream, h1, att_src1, att_dst1, a_s1, a_d1);
    hipLaunchKernelGGL(k_agg1,     dim3(3125),  dim3(256), 0, stream, offsets, counts, sorted_src,
                       a_s1, a_d1, h1, b1, W2, att_src2, att_dst2, gbuf, a_s2, a_d2);
    hipLaunchKernelGGL(k_agg2,     dim3(3125),  dim3(256), 0, stream, offsets, counts, sorted_src,
                       a_s2, a_d2, gbuf, b2, outp);
}

// Round 3
// 838.641 us; speedup vs baseline: 1.2345x; 1.2345x over previous
//
#include <hip/hip_runtime.h>

#define N_NODES 100000
#define E_EDGES 3200000
#define F_IN    1433
#define K_PAD   1440   // w1t padded K
#define NCH     98     // scan chunks of 1024
#define ROWS    16
#define SLAB    (ROWS * F_IN)   // 22928 floats per block

typedef _Float16 f16x4 __attribute__((ext_vector_type(4)));
typedef _Float16 f16x8 __attribute__((ext_vector_type(8)));
typedef float    f32x4 __attribute__((ext_vector_type(4)));

// ---------------- W1^T fp16 [64][K_PAD], zero-padded ----------------
__global__ void k_prep_w1t(const float* __restrict__ w1, _Float16* __restrict__ w1t) {
    int idx = blockIdx.x * 256 + threadIdx.x;           // 64*1440 = 92160
    if (idx >= 64 * K_PAD) return;
    int n = idx / K_PAD, k = idx % K_PAD;
    float v = (k < F_IN) ? w1[(size_t)k * 64 + n] : 0.f;
    w1t[idx] = (_Float16)v;
}

__global__ void k_zero(int* __restrict__ counts) {
    int i = blockIdx.x * 256 + threadIdx.x;
    if (i < N_NODES) counts[i] = 0;
}

__global__ void k_hist(const int* __restrict__ dst, int* __restrict__ counts) {
    int e = blockIdx.x * 256 + threadIdx.x;
    if (e < E_EDGES) atomicAdd(&counts[dst[e]], 1);
}

// ---------------- exclusive scan of counts (chunked) ----------------
__global__ void k_scan_a(const int* __restrict__ counts, int* __restrict__ csum) {
    __shared__ int sh[256];
    int b = blockIdx.x, t = threadIdx.x;
    int s = 0;
    for (int j = 0; j < 4; ++j) {
        int idx = b * 1024 + j * 256 + t;
        if (idx < N_NODES) s += counts[idx];
    }
    sh[t] = s; __syncthreads();
    for (int off = 128; off > 0; off >>= 1) {
        if (t < off) sh[t] += sh[t + off];
        __syncthreads();
    }
    if (t == 0) csum[b] = sh[0];
}

__global__ void k_scan_b(int* __restrict__ csum) {
    if (threadIdx.x == 0 && blockIdx.x == 0) {
        int run = 0;
        for (int i = 0; i < NCH; ++i) { int t = csum[i]; csum[i] = run; run += t; }
    }
}

__global__ void k_scan_c(const int* __restrict__ counts, const int* __restrict__ csum,
                         int* __restrict__ offsets, int* __restrict__ cursor) {
    __shared__ int sh[256];
    int b = blockIdx.x, t = threadIdx.x;
    int base = b * 1024 + t * 4;
    int c0 = (base + 0 < N_NODES) ? counts[base + 0] : 0;
    int c1 = (base + 1 < N_NODES) ? counts[base + 1] : 0;
    int c2 = (base + 2 < N_NODES) ? counts[base + 2] : 0;
    int c3 = (base + 3 < N_NODES) ? counts[base + 3] : 0;
    int tot = c0 + c1 + c2 + c3;
    sh[t] = tot; __syncthreads();
    for (int off = 1; off < 256; off <<= 1) {
        int v = (t >= off) ? sh[t - off] : 0;
        __syncthreads();
        sh[t] += v;
        __syncthreads();
    }
    int excl = sh[t] - tot;
    int o = csum[b] + excl;
    if (base + 0 < N_NODES) { offsets[base + 0] = o;            cursor[base + 0] = o; }
    if (base + 1 < N_NODES) { int q = o + c0;      offsets[base + 1] = q; cursor[base + 1] = q; }
    if (base + 2 < N_NODES) { int q = o + c0 + c1; offsets[base + 2] = q; cursor[base + 2] = q; }
    if (base + 3 < N_NODES) { int q = o + c0 + c1 + c2; offsets[base + 3] = q; cursor[base + 3] = q; }
}

__global__ void k_scatter(const int* __restrict__ src, const int* __restrict__ dst,
                          int* __restrict__ cursor, int* __restrict__ sorted_src) {
    int e = blockIdx.x * 256 + threadIdx.x;
    if (e < E_EDGES) {
        int d = dst[e];
        int pos = atomicAdd(&cursor[d], 1);
        sorted_src[pos] = src[e];
    }
}

// ---------------- GEMM1: h1[N,64] = x @ W1  (flat-slab staging, fp16 MFMA) ----------------
// Each block: 16 rows of x = flat contiguous 91712 B (16B-aligned). Stage as fp16
// into a flat LDS slab (one barrier), then 90 MFMA K-steps per wave (wave = n-tile).
__global__ __launch_bounds__(256) void k_gemm1(const float* __restrict__ x,
                                               const _Float16* __restrict__ w1t,
                                               _Float16* __restrict__ h1) {
    __shared__ _Float16 As[SLAB];   // 45856 B -> 3 blocks/CU
    const int tid = threadIdx.x;
    const size_t base = (size_t)blockIdx.x * SLAB;

    #pragma unroll
    for (int r = 0; r < 22; ++r) {
        int flat = r * 1024 + tid * 4;
        float4 v = *(const float4*)(x + base + flat);
        f16x4 hv = { (_Float16)v.x, (_Float16)v.y, (_Float16)v.z, (_Float16)v.w };
        *(f16x4*)(&As[flat]) = hv;
    }
    if (tid < 100) {               // tail: 22928 - 22528 = 400 floats
        int flat = 22528 + tid * 4;
        float4 v = *(const float4*)(x + base + flat);
        f16x4 hv = { (_Float16)v.x, (_Float16)v.y, (_Float16)v.z, (_Float16)v.w };
        *(f16x4*)(&As[flat]) = hv;
    }
    __syncthreads();

    const int lane = tid & 63;
    const int wave = tid >> 6;     // n-tile: cols wave*16..+15
    const int l16  = lane & 15;
    const int l4   = lane >> 4;
    const int arow = l16 * F_IN;   // A row base (flat halfword index)
    const _Float16* bp = w1t + (size_t)(wave * 16 + l16) * K_PAD;

    f32x4 acc = {};
    for (int c = 0; c < 11; ++c) {           // 88 full steps in chunks of 8
        f16x4 bb[8];
        #pragma unroll
        for (int u = 0; u < 8; ++u)
            bb[u] = *(const f16x4*)(bp + (c * 8 + u) * 16 + l4 * 4);
        #pragma unroll
        for (int u = 0; u < 8; ++u) {
            int k = (c * 8 + u) * 16 + l4 * 4;
            f16x4 a = { As[arow + k], As[arow + k + 1], As[arow + k + 2], As[arow + k + 3] };
            acc = __builtin_amdgcn_mfma_f32_16x16x16f16(a, bb[u], acc, 0, 0, 0);
        }
    }
    {   // step 88 (k max 1423 < 1433, full)
        int k = 88 * 16 + l4 * 4;
        f16x4 b = *(const f16x4*)(bp + k);
        f16x4 a = { As[arow + k], As[arow + k + 1], As[arow + k + 2], As[arow + k + 3] };
        acc = __builtin_amdgcn_mfma_f32_16x16x16f16(a, b, acc, 0, 0, 0);
    }
    {   // step 89 tail: k in [1424,1440), zero beyond 1432
        int k = 89 * 16 + l4 * 4;
        f16x4 b = *(const f16x4*)(bp + k);
        f16x4 a = { (k     < F_IN) ? As[arow + k]     : (_Float16)0.f,
                    (k + 1 < F_IN) ? As[arow + k + 1] : (_Float16)0.f,
                    (k + 2 < F_IN) ? As[arow + k + 2] : (_Float16)0.f,
                    (k + 3 < F_IN) ? As[arow + k + 3] : (_Float16)0.f };
        acc = __builtin_amdgcn_mfma_f32_16x16x16f16(a, b, acc, 0, 0, 0);
    }
    const int r0 = blockIdx.x * ROWS;
    #pragma unroll
    for (int j = 0; j < 4; ++j) {
        int r = r0 + l4 * 4 + j;   // C: col = lane&15, row = (lane>>4)*4 + reg
        h1[(size_t)r * 64 + wave * 16 + l16] = (_Float16)acc[j];
    }
}

// ---------------- per-node attention coefficients, layer 1 (fp16 h1) ----------------
__global__ void k_att1(const _Float16* __restrict__ h1, const float* __restrict__ att_src,
                       const float* __restrict__ att_dst,
                       float* __restrict__ a_s, float* __restrict__ a_d) {
    int n = blockIdx.x * 256 + threadIdx.x;
    if (n >= N_NODES) return;
    const f16x8* hp = (const f16x8*)(h1 + (size_t)n * 64);
    #pragma unroll
    for (int h = 0; h < 8; ++h) {
        f16x8 v = hp[h];
        const float* as = att_src + h * 8;
        const float* ad = att_dst + h * 8;
        float s = 0.f, d = 0.f;
        #pragma unroll
        for (int c = 0; c < 8; ++c) {
            float f = (float)v[c];
            s += f * as[c];
            d += f * ad[c];
        }
        a_s[n * 8 + h] = s;
        a_d[n * 8 + h] = d;
    }
}

// ---------------- layer-1 aggregate + ELU + layer-2 prep (1 node / wave) ----------------
// lane = es*8 + h : 8 edge-slots x 8 heads
__global__ __launch_bounds__(256) void k_agg1(
    const int* __restrict__ offsets, const int* __restrict__ counts,
    const int* __restrict__ sorted_src,
    const float* __restrict__ a_s1, const float* __restrict__ a_d1,
    const _Float16* __restrict__ h1, const float* __restrict__ b1,
    const float* __restrict__ w2, const float* __restrict__ att_src2,
    const float* __restrict__ att_dst2,
    _Float16* __restrict__ g, float* __restrict__ a_s2, float* __restrict__ a_d2) {
    const int lane = threadIdx.x & 63;
    const int wave = threadIdx.x >> 6;
    const int h    = lane & 7;
    const int es   = lane >> 3;
    const int n    = blockIdx.x * 4 + wave;     // 25000*4 = 100000 exact
    const int start = offsets[n];
    const int cnt   = counts[n];
    const float adn = a_d1[n * 8 + h];
    float et = a_s1[n * 8 + h] + adn;
    const float e_self = et > 0.f ? et : 0.2f * et;

    float m = (es == 0) ? e_self : -1e30f;
    for (int i = es; i < cnt; i += 8) {
        int s = sorted_src[start + i];
        float e = a_s1[s * 8 + h] + adn;
        e = e > 0.f ? e : 0.2f * e;
        m = fmaxf(m, e);
    }
    m = fmaxf(m, __shfl_xor(m, 8));
    m = fmaxf(m, __shfl_xor(m, 16));
    m = fmaxf(m, __shfl_xor(m, 32));            // per-head max across edge-slots

    float denom = 0.f;
    float acc[8] = {0.f,0.f,0.f,0.f,0.f,0.f,0.f,0.f};
    if (es == 0) {
        float p = __expf(e_self - m);
        denom = p;
        f16x8 hv = *(const f16x8*)(h1 + (size_t)n * 64 + h * 8);
        #pragma unroll
        for (int c = 0; c < 8; ++c) acc[c] = p * (float)hv[c];
    }
    for (int i = es; i < cnt; i += 8) {
        int s = sorted_src[start + i];
        float e = a_s1[s * 8 + h] + adn;
        e = e > 0.f ? e : 0.2f * e;
        float p = __expf(e - m);
        denom += p;
        f16x8 hv = *(const f16x8*)(h1 + (size_t)s * 64 + h * 8);
        #pragma unroll
        for (int c = 0; c < 8; ++c) acc[c] += p * (float)hv[c];
    }
    denom += __shfl_xor(denom, 8);
    denom += __shfl_xor(denom, 16);
    denom += __shfl_xor(denom, 32);
    #pragma unroll
    for (int c = 0; c < 8; ++c) {
        acc[c] += __shfl_xor(acc[c], 8);
        acc[c] += __shfl_xor(acc[c], 16);
        acc[c] += __shfl_xor(acc[c], 32);
    }
    float inv = 1.f / (denom + 1e-16f);
    float hc[8];
    #pragma unroll
    for (int c = 0; c < 8; ++c) {
        float v = acc[c] * inv;
        v += __shfl_xor(v, 1);
        v += __shfl_xor(v, 2);
        v += __shfl_xor(v, 4);                  // mean over heads
        float o = 0.125f * v + b1[c];
        hc[c] = o > 0.f ? o : expm1f(o);        // ELU
    }
    if (lane == 0) {
        float s2 = 0.f, d2 = 0.f;
        f16x8 gr;
        #pragma unroll
        for (int j = 0; j < 7; ++j) {
            float t = 0.f;
            #pragma unroll
            for (int c = 0; c < 8; ++c) t += hc[c] * w2[c * 7 + j];
            gr[j] = (_Float16)t;
            s2 += t * att_src2[j];
            d2 += t * att_dst2[j];
        }
        gr[7] = (_Float16)0.f;
        *(f16x8*)(g + (size_t)n * 8) = gr;
        a_s2[n] = s2;
        a_d2[n] = d2;
    }
}

// ---------------- layer-2 aggregate + log_softmax (8 lanes/node, fp16 g) ----------------
__global__ __launch_bounds__(256) void k_agg2(
    const int* __restrict__ offsets, const int* __restrict__ counts,
    const int* __restrict__ sorted_src,
    const float* __restrict__ a_s2, const float* __restrict__ a_d2,
    const _Float16* __restrict__ g, const float* __restrict__ b2,
    float* __restrict__ outp) {
    const int tid  = threadIdx.x;
    const int lane = tid & 63;
    const int wave = tid >> 6;
    const int grp  = lane >> 3;
    const int s    = lane & 7;
    const int n    = blockIdx.x * 32 + wave * 8 + grp;
    const int start = offsets[n];
    const int cnt   = counts[n];
    const float adn = a_d2[n];
    float et = a_s2[n] + adn;
    const float e_self = et > 0.f ? et : 0.2f * et;
    float m = (s == 0) ? e_self : -1e30f;
    for (int i = s; i < cnt; i += 8) {
        int sc = sorted_src[start + i];
        float e = a_s2[sc] + adn;
        e = e > 0.f ? e : 0.2f * e;
        m = fmaxf(m, e);
    }
    m = fmaxf(m, __shfl_xor(m, 1, 8));
    m = fmaxf(m, __shfl_xor(m, 2, 8));
    m = fmaxf(m, __shfl_xor(m, 4, 8));
    float denom = 0.f;
    float acc[8] = {0.f,0.f,0.f,0.f,0.f,0.f,0.f,0.f};
    if (s == 0) {
        float p = __expf(e_self - m);
        denom = p;
        f16x8 gv = *(const f16x8*)(g + (size_t)n * 8);
        #pragma unroll
        for (int c = 0; c < 8; ++c) acc[c] = p * (float)gv[c];
    }
    for (int i = s; i < cnt; i += 8) {
        int sc = sorted_src[start + i];
        float e = a_s2[sc] + adn;
        e = e > 0.f ? e : 0.2f * e;
        float p = __expf(e - m);
        denom += p;
        f16x8 gv = *(const f16x8*)(g + (size_t)sc * 8);
        #pragma unroll
        for (int c = 0; c < 8; ++c) acc[c] += p * (float)gv[c];
    }
    denom += __shfl_xor(denom, 1, 8);
    denom += __shfl_xor(denom, 2, 8);
    denom += __shfl_xor(denom, 4, 8);
    #pragma unroll
    for (int c = 0; c < 8; ++c) {
        acc[c] += __shfl_xor(acc[c], 1, 8);
        acc[c] += __shfl_xor(acc[c], 2, 8);
        acc[c] += __shfl_xor(acc[c], 4, 8);
    }
    float inv = 1.f / (denom + 1e-16f);
    float o[7]; float mx = -1e30f;
    #pragma unroll
    for (int c = 0; c < 7; ++c) { o[c] = acc[c] * inv + b2[c]; mx = fmaxf(mx, o[c]); }
    float se = 0.f;
    #pragma unroll
    for (int c = 0; c < 7; ++c) se += __expf(o[c] - mx);
    float ls = mx + logf(se);
    if (s < 7) outp[n * 7 + s] = o[s] - ls;
}

extern "C" void kernel_launch(void* const* d_in, const int* in_sizes, int n_in,
                              void* d_out, int out_size, void* d_ws, size_t ws_size,
                              hipStream_t stream) {
    const float* x        = (const float*)d_in[0];
    const int*   ei       = (const int*)d_in[1];
    const float* W1       = (const float*)d_in[2];
    const float* att_src1 = (const float*)d_in[3];
    const float* att_dst1 = (const float*)d_in[4];
    const float* b1       = (const float*)d_in[5];
    const float* W2       = (const float*)d_in[6];
    const float* att_src2 = (const float*)d_in[7];
    const float* att_dst2 = (const float*)d_in[8];
    const float* b2       = (const float*)d_in[9];
    const int* src = ei;
    const int* dst = ei + E_EDGES;

    char* ws = (char*)d_ws;
    size_t off = 0;
    auto alloc = [&](size_t bytes) -> char* {
        char* p = ws + off;
        off = (off + bytes + 255) & ~(size_t)255;
        return p;
    };
    _Float16* h1         = (_Float16*)alloc((size_t)N_NODES * 64 * 2);
    float*    a_s1       = (float*)   alloc((size_t)N_NODES * 8 * 4);
    float*    a_d1       = (float*)   alloc((size_t)N_NODES * 8 * 4);
    _Float16* w1t        = (_Float16*)alloc((size_t)64 * K_PAD * 2);
    int*      counts     = (int*)     alloc((size_t)N_NODES * 4);
    int*      offsets    = (int*)     alloc((size_t)N_NODES * 4);
    int*      cursor     = (int*)     alloc((size_t)N_NODES * 4);
    int*      csum       = (int*)     alloc((size_t)NCH * 4);
    int*      sorted_src = (int*)     alloc((size_t)E_EDGES * 4);
    _Float16* gbuf       = (_Float16*)alloc((size_t)N_NODES * 8 * 2);
    float*    a_s2       = (float*)   alloc((size_t)N_NODES * 4);
    float*    a_d2       = (float*)   alloc((size_t)N_NODES * 4);
    float*    outp       = (float*)d_out;

    hipLaunchKernelGGL(k_prep_w1t, dim3(360),   dim3(256), 0, stream, W1, w1t);
    hipLaunchKernelGGL(k_zero,     dim3(391),   dim3(256), 0, stream, counts);
    hipLaunchKernelGGL(k_hist,     dim3(12500), dim3(256), 0, stream, dst, counts);
    hipLaunchKernelGGL(k_scan_a,   dim3(NCH),   dim3(256), 0, stream, counts, csum);
    hipLaunchKernelGGL(k_scan_b,   dim3(1),     dim3(1),   0, stream, csum);
    hipLaunchKernelGGL(k_scan_c,   dim3(NCH),   dim3(256), 0, stream, counts, csum, offsets, cursor);
    hipLaunchKernelGGL(k_scatter,  dim3(12500), dim3(256), 0, stream, src, dst, cursor, sorted_src);
    hipLaunchKernelGGL(k_gemm1,    dim3(6250),  dim3(256), 0, stream, x, w1t, h1);
    hipLaunchKernelGGL(k_att1,     dim3(391),   dim3(256), 0, stream, h1, att_src1, att_dst1, a_s1, a_d1);
    hipLaunchKernelGGL(k_agg1,     dim3(25000), dim3(256), 0, stream, offsets, counts, sorted_src,
                       a_s1, a_d1, h1, b1, W2, att_src2, att_dst2, gbuf, a_s2, a_d2);
    hipLaunchKernelGGL(k_agg2,     dim3(3125),  dim3(256), 0, stream, offsets, counts, sorted_src,
                       a_s2, a_d2, gbuf, b2, outp);
}